// Round 1
// baseline (369.528 us; speedup 1.0000x reference)
//
#include <hip/hip_runtime.h>
#include <math.h>

// Problem constants (from reference): B=128, S=4096, D_IN=128, E=1, D_OUT=64, DELAY=2
#define S_LEN   4096
#define BATCH   128
#define DIN     128
#define DELAY_N 2
#define NDIFF   (S_LEN - DELAY_N)      // 4094
#define SCHUNK  512
#define NCHUNK  (S_LEN / SCHUNK)       // 8
#define NBLK    (BATCH * NCHUNK)       // 1024

// Main streaming kernel: per block = one (batch b, s-chunk) pair.
// Computes t[s] = w2_0*relu(<x,w1_0>+b1_0) + w2_1*relu(<x,w1_1>+b1_1) + b2
// for rows [s0, s0+SCHUNK+2), then partial sums of log|t[s+2]-t[s]|+eps
// and its square, written deterministically to partials[blk][2].
__global__ __launch_bounds__(256)
void mle_main(const float* __restrict__ x,
              const float* __restrict__ w1,
              const float* __restrict__ b1,
              const float* __restrict__ w2,
              const float* __restrict__ b2,
              double* __restrict__ partials) {
  const int blk  = blockIdx.x;
  const int b    = blk >> 3;               // NCHUNK == 8
  const int s0   = (blk & 7) * SCHUNK;
  const int tid  = threadIdx.x;
  const int lane = tid & 63;
  const int wave = tid >> 6;               // 4 waves/block
  const int half = lane >> 5;              // 0 or 1: which row of the pair
  const int l    = lane & 31;              // position within the row (float4 granularity)

  __shared__ float  tbuf[SCHUNK + DELAY_N];
  __shared__ double wpart[8];

  // Per-lane slice of the two w1 rows (each lane owns 4 fixed columns).
  const float4 wa = *(const float4*)(w1 + l * 4);         // w1[0, 4l..4l+3]
  const float4 wb = *(const float4*)(w1 + DIN + l * 4);   // w1[1, 4l..4l+3]
  const float b1a = b1[0], b1b = b1[1];
  const float w2a = w2[0], w2b = w2[1], b20 = b2[0];

  // Rows of t this block computes (always even: 514 or 512 for the last chunk)
  const int R = min(SCHUNK + DELAY_N, S_LEN - s0);
  const float* xb = x + ((size_t)b * S_LEN + (size_t)s0) * DIN;

  // Each wave processes row-pairs p = wave, wave+4, ... ; U-way unrolled so
  // U independent 1KiB loads are in flight per wave.
  constexpr int U = 4;
  for (int pb = wave; 2 * pb < R; pb += 4 * U) {
    float4 v[U];
    int act = 0;
    #pragma unroll
    for (int u = 0; u < U; ++u) {
      const int p = pb + 4 * u;
      if (2 * p < R) {                      // wave-uniform predicate, R is even
        act |= (1 << u);
        v[u] = *(const float4*)(xb + (size_t)(2 * p + half) * DIN + l * 4);
      }
    }
    #pragma unroll
    for (int u = 0; u < U; ++u) {
      if (!(act & (1 << u))) continue;
      float d0 = v[u].x * wa.x + v[u].y * wa.y + v[u].z * wa.z + v[u].w * wa.w;
      float d1 = v[u].x * wb.x + v[u].y * wb.y + v[u].z * wb.z + v[u].w * wb.w;
      // reduce across the 32 lanes of this half (xor masks <32 stay in-half)
      #pragma unroll
      for (int m = 16; m >= 1; m >>= 1) {
        d0 += __shfl_xor(d0, m);
        d1 += __shfl_xor(d1, m);
      }
      if (l == 0) {
        const float t = w2a * fmaxf(d0 + b1a, 0.0f)
                      + w2b * fmaxf(d1 + b1b, 0.0f) + b20;
        tbuf[2 * (pb + 4 * u) + half] = t;
      }
    }
  }
  __syncthreads();

  // Partial sums of log_diff and log_diff^2 over this chunk's valid s-range.
  double ls = 0.0, ls2 = 0.0;
  const int nd = min(SCHUNK, NDIFF - s0);   // 512 (or 510 for last chunk)
  for (int i = tid; i < nd; i += 256) {
    const float d  = fabsf(tbuf[i + DELAY_N] - tbuf[i]);
    const float ld = logf(d + 1e-6f);
    ls  += (double)ld;
    ls2 += (double)ld * (double)ld;
  }
  #pragma unroll
  for (int m = 32; m >= 1; m >>= 1) {
    ls  += __shfl_xor(ls, m);
    ls2 += __shfl_xor(ls2, m);
  }
  if (lane == 0) { wpart[wave * 2] = ls; wpart[wave * 2 + 1] = ls2; }
  __syncthreads();
  if (tid == 0) {
    const double a = wpart[0] + wpart[2] + wpart[4] + wpart[6];
    const double q = wpart[1] + wpart[3] + wpart[5] + wpart[7];
    partials[blk * 2 + 0] = a;
    partials[blk * 2 + 1] = q;
  }
}

// Finalize: per batch b, fold 8 chunk-partials, compute mean/std (ddof=1),
// out[b, j] = tanh(mean*w3[j,0] + std*w3[j,1] + b3[j]), broadcast to (64,64).
__global__ __launch_bounds__(256)
void mle_final(const double* __restrict__ partials,
               const float* __restrict__ w3,
               const float* __restrict__ b3,
               float* __restrict__ out) {
  const int b   = blockIdx.x;
  const int tid = threadIdx.x;

  double sum = 0.0, sumsq = 0.0;
  #pragma unroll
  for (int c = 0; c < NCHUNK; ++c) {
    sum   += partials[(b * NCHUNK + c) * 2 + 0];
    sumsq += partials[(b * NCHUNK + c) * 2 + 1];
  }
  const double n    = (double)NDIFF;
  const double mean = sum / n;
  double var = (sumsq - n * mean * mean) / (n - 1.0);
  if (var < 0.0) var = 0.0;
  const float meanf = (float)mean;
  const float stdf  = (float)sqrt(var);

  __shared__ float vals[64];
  if (tid < 64) {
    vals[tid] = tanhf(meanf * w3[tid * 2] + stdf * w3[tid * 2 + 1] + b3[tid]);
  }
  __syncthreads();

  // out[b][i][j] = vals[j]; each thread emits one float4 pattern 4 times.
  const int j = (4 * tid) & 63;
  const float4 v = make_float4(vals[j], vals[j + 1], vals[j + 2], vals[j + 3]);
  float4* o = (float4*)(out + (size_t)b * (64 * 64));
  #pragma unroll
  for (int k = 0; k < 4; ++k) {
    o[tid + k * 256] = v;
  }
}

extern "C" void kernel_launch(void* const* d_in, const int* in_sizes, int n_in,
                              void* d_out, int out_size, void* d_ws, size_t ws_size,
                              hipStream_t stream) {
  const float* x  = (const float*)d_in[0];
  const float* w1 = (const float*)d_in[1];
  const float* b1 = (const float*)d_in[2];
  const float* w2 = (const float*)d_in[3];
  const float* b2 = (const float*)d_in[4];
  const float* w3 = (const float*)d_in[5];
  const float* b3 = (const float*)d_in[6];
  float* out = (float*)d_out;

  // Deterministic per-block partials in workspace: NBLK * 2 doubles = 16 KiB.
  double* partials = (double*)d_ws;

  mle_main <<<NBLK,  256, 0, stream>>>(x, w1, b1, w2, b2, partials);
  mle_final<<<BATCH, 256, 0, stream>>>(partials, w3, b3, out);
}